// Round 5
// baseline (545.399 us; speedup 1.0000x reference)
//
#include <hip/hip_runtime.h>
#include <hip/hip_bf16.h>

#define DIN 256
#define DHID 128
#define NCLS 47
#define BSHIFT 9                 // bucket = node >> 9  (512 nodes/bucket)
#define BNODES 512

typedef __attribute__((ext_vector_type(8))) short short8;   // 8 bf16 (4 VGPRs)
typedef __attribute__((ext_vector_type(4))) float f32x4;

__device__ __forceinline__ short f2bf(float f) {
    __bf16 b = (__bf16)f;                 // RNE convert
    return __builtin_bit_cast(short, b);
}
__device__ __forceinline__ float bfu(unsigned int u) {   // low 16 bits = bf16
    return __uint_as_float(u << 16);
}
__device__ __forceinline__ float bfh(unsigned int u) {   // high 16 bits = bf16
    return __uint_as_float(u & 0xffff0000u);
}
__device__ __forceinline__ unsigned int pack2(float lo, float hi) {
    return (unsigned int)(unsigned short)f2bf(lo)
         | ((unsigned int)(unsigned short)f2bf(hi) << 16);
}
// a[j] += row[j] (8 bf16 in one uint4)
__device__ __forceinline__ void add8(float* a, uint4 v) {
    a[0] += bfu(v.x); a[1] += bfh(v.x);
    a[2] += bfu(v.y); a[3] += bfh(v.y);
    a[4] += bfu(v.z); a[5] += bfh(v.z);
    a[6] += bfu(v.w); a[7] += bfh(v.w);
}
// a[j] += d * row[j]
__device__ __forceinline__ void fma8(float* a, uint4 v, float d) {
    a[0] += d * bfu(v.x); a[1] += d * bfh(v.x);
    a[2] += d * bfu(v.y); a[3] += d * bfh(v.y);
    a[4] += d * bfu(v.z); a[5] += d * bfh(v.z);
    a[6] += d * bfu(v.w); a[7] += d * bfh(v.w);
}

// ===== L1: weight swizzles + per-node degree count (global atomics) ========
// blocks 0..15: W1 swizzle; 16..19: W2 swizzle; >=20: degree atomics.
// High-TLP (1563 deg blocks) replaces the serialized LDS-histogram kernel.
__global__ __launch_bounds__(256) void k_prep(const float* __restrict__ W1,
                                              const float* __restrict__ W2,
                                              short* __restrict__ W1s,
                                              short* __restrict__ W2s,
                                              const int* __restrict__ dst,
                                              int* __restrict__ degc,
                                              int* __restrict__ btot, int E) {
    int blk = blockIdx.x, t = threadIdx.x;
    if (blk < 16) {                      // W1 -> B-fragment swizzle
        int tid = blk * 256 + t;         // 0..4095
        int frag = tid >> 6, lane = tid & 63;
        int kt = frag >> 3, nt = frag & 7;
        int quad = lane >> 4, col = lane & 15;
        #pragma unroll
        for (int j = 0; j < 8; ++j) {
            int k = kt * 32 + quad * 8 + j;
            W1s[(size_t)tid * 8 + j] = f2bf(W1[k * DHID + nt * 16 + col]);
        }
    } else if (blk < 20) {               // W2 -> B-fragment swizzle (pad N to 64)
        int tid = (blk - 16) * 256 + t;  // 0..1023
        int frag = tid >> 6, lane = tid & 63;
        int kt = frag >> 2, nt = frag & 3;
        int quad = lane >> 4, col = lane & 15;
        int c = nt * 16 + col;
        #pragma unroll
        for (int j = 0; j < 8; ++j) {
            int k = kt * 32 + quad * 8 + j;
            float v = (c < NCLS) ? W2[k * NCLS + c] : 0.0f;
            W2s[(size_t)tid * 8 + j] = f2bf(v);
        }
    } else {                             // degree count: 4 edges/thread
        __shared__ int lh[256];          // per-block bucket histogram
        lh[t] = 0;
        __syncthreads();
        int p = blk - 20;
        int e4 = E >> 2;
        int idx = p * 256 + t;
        if (idx < e4) {
            int4 d4 = ((const int4*)dst)[idx];
            atomicAdd(&degc[d4.x], 1);  atomicAdd(&lh[d4.x >> BSHIFT], 1);
            atomicAdd(&degc[d4.y], 1);  atomicAdd(&lh[d4.y >> BSHIFT], 1);
            atomicAdd(&degc[d4.z], 1);  atomicAdd(&lh[d4.z >> BSHIFT], 1);
            atomicAdd(&degc[d4.w], 1);  atomicAdd(&lh[d4.w >> BSHIFT], 1);
        }
        if (p == 0 && t < (E & 3)) {     // tail edges
            int d = dst[(e4 << 2) + t];
            atomicAdd(&degc[d], 1);  atomicAdd(&lh[d >> BSHIFT], 1);
        }
        __syncthreads();
        if (lh[t]) atomicAdd(&btot[t], lh[t]);
    }
}

// 256-thread exclusive scan of btot -> lbase[0..255]; ends synced
__device__ __forceinline__ void scan_btot(const int* __restrict__ btot, int NB,
                                          int* lbase, int* wsum) {
    int t = threadIdx.x;
    int v = (t < NB) ? btot[t] : 0;
    int incl = v;
    int lane = t & 63, w = t >> 6;
    #pragma unroll
    for (int off = 1; off < 64; off <<= 1) {
        int u = __shfl_up(incl, off, 64);
        if (lane >= off) incl += u;
    }
    if (lane == 63) wsum[w] = incl;
    __syncthreads();
    int wadd = 0;
    for (int i = 0; i < w; ++i) wadd += wsum[i];
    lbase[t] = wadd + incl - v;   // exclusive
    __syncthreads();
}

// ===== L2: CSR offsets (two-level scan) PARALLEL gemm1 (disjoint blocks) ===
// blocks 0..NB-1: bucket-base scan + per-bucket 512-degree pair-scan ->
//   beg/cur/degi/dinv. blocks >= NB: gemm1 hb = bf16(x @ W1) hides it.
__global__ __launch_bounds__(256) void k_build_gemm1(const int* __restrict__ btot,
                                                     const int* __restrict__ degc,
                                                     int* __restrict__ degi,
                                                     int* __restrict__ beg,
                                                     int* __restrict__ cur,
                                                     float* __restrict__ dinv,
                                                     int n, int NB,
                                                     const float* __restrict__ x,
                                                     const short* __restrict__ W1s,
                                                     short* __restrict__ hb) {
    __shared__ __align__(16) char smem[65536];
    int blk = blockIdx.x, t = threadIdx.x;

    if (blk < NB) {
        int* lbase = (int*)smem;             // 1024 B
        int* wsum  = (int*)(smem + 1024);    //   16 B
        scan_btot(btot, NB, lbase, wsum);
        int base = lbase[blk];
        int node0 = blk << BSHIFT;
        int i0 = node0 + 2 * t;              // degc padded to bucket multiple
        int v0 = degc[i0], v1 = degc[i0 + 1];
        int s = v0 + v1;
        int incl = s;
        int lane = t & 63, w = t >> 6;
        #pragma unroll
        for (int off = 1; off < 64; off <<= 1) {
            int u = __shfl_up(incl, off, 64);
            if (lane >= off) incl += u;
        }
        if (lane == 63) wsum[w] = incl;
        __syncthreads();
        int wadd = 0;
        for (int i = 0; i < w; ++i) wadd += wsum[i];
        int ex = wadd + incl - s;
        if (i0 < n) {
            degi[i0] = v0;
            beg[i0]  = base + ex;
            cur[i0]  = base + ex;
            dinv[i0] = rsqrtf((float)(v0 + 1));
        }
        if (i0 + 1 < n) {
            degi[i0 + 1] = v1;
            beg[i0 + 1]  = base + ex + v0;
            cur[i0 + 1]  = base + ex + v0;
            dinv[i0 + 1] = rsqrtf((float)(v1 + 1));
        }
    } else {
        // ---------------- gemm1 path: hb = bf16(x @ W1) ----------------
        short* lw = (short*)smem;     // 64 KB: full swizzled W1
        {
            const uint4* g = (const uint4*)W1s;
            uint4* l = (uint4*)lw;
            for (int i = t; i < 4096; i += 256) l[i] = g[i];
        }
        __syncthreads();

        int bid = blk - NB;
        int wave = t >> 6, lane = t & 63;
        int quad = lane >> 4, lrow = lane & 15;
        long long rowbase = (long long)bid * 128 + wave * 32;

        f32x4 acc[2][8];
        #pragma unroll
        for (int rt = 0; rt < 2; ++rt)
            #pragma unroll
            for (int nt = 0; nt < 8; ++nt) acc[rt][nt] = (f32x4){0.f, 0.f, 0.f, 0.f};

        const short8* lf = (const short8*)lw;

        #pragma unroll
        for (int kt = 0; kt < 8; ++kt) {
            int k0 = kt * 32 + quad * 8;
            short8 a[2];
            #pragma unroll
            for (int rt = 0; rt < 2; ++rt) {
                long long row = rowbase + rt * 16 + lrow;
                float4 v0 = {0.f,0.f,0.f,0.f}, v1 = {0.f,0.f,0.f,0.f};
                if (row < n) {
                    const float* xp = x + row * DIN + k0;
                    v0 = *(const float4*)xp;
                    v1 = *(const float4*)(xp + 4);
                }
                short8 av;
                av[0] = f2bf(v0.x); av[1] = f2bf(v0.y); av[2] = f2bf(v0.z); av[3] = f2bf(v0.w);
                av[4] = f2bf(v1.x); av[5] = f2bf(v1.y); av[6] = f2bf(v1.z); av[7] = f2bf(v1.w);
                a[rt] = av;
            }
            #pragma unroll
            for (int nt = 0; nt < 8; ++nt) {
                short8 b = lf[(kt * 8 + nt) * 64 + lane];
                acc[0][nt] = __builtin_amdgcn_mfma_f32_16x16x32_bf16(a[0], b, acc[0][nt], 0, 0, 0);
                acc[1][nt] = __builtin_amdgcn_mfma_f32_16x16x32_bf16(a[1], b, acc[1][nt], 0, 0, 0);
            }
        }
        #pragma unroll
        for (int rt = 0; rt < 2; ++rt)
            #pragma unroll
            for (int nt = 0; nt < 8; ++nt)
                #pragma unroll
                for (int r = 0; r < 4; ++r) {
                    long long row = rowbase + rt * 16 + quad * 4 + r;
                    if (row < n) hb[row * DHID + nt * 16 + lrow] = f2bf(acc[rt][nt][r]);
                }
    }
}

// ===== L3: slot-atomic scatter: bbuf[atomicAdd(cur[dst])] = src ============
// per-node edge order arbitrary (sum commutes). High TLP, no LDS.
__global__ __launch_bounds__(256) void k_scatter(const int* __restrict__ src,
                                                 const int* __restrict__ dst,
                                                 int* __restrict__ cur,
                                                 int* __restrict__ bbuf, int E) {
    int idx = blockIdx.x * 256 + threadIdx.x;
    int e4 = E >> 2;
    if (idx < e4) {
        int4 s4 = ((const int4*)src)[idx];
        int4 d4 = ((const int4*)dst)[idx];
        bbuf[atomicAdd(&cur[d4.x], 1)] = s4.x;
        bbuf[atomicAdd(&cur[d4.y], 1)] = s4.y;
        bbuf[atomicAdd(&cur[d4.z], 1)] = s4.z;
        bbuf[atomicAdd(&cur[d4.w], 1)] = s4.w;
    }
    if (blockIdx.x == 0 && threadIdx.x < (E & 3)) {   // tail edges
        int i = (e4 << 2) + threadIdx.x;
        bbuf[atomicAdd(&cur[dst[i]], 1)] = src[i];
    }
}

// ===== L4: gather1 — proven round-1 interleave, per-edge dinv ==============
// wave = 1 node; 4 edge-groups x 16 dim-lanes; 4 uint4 gathers in flight.
__global__ __launch_bounds__(256) void k_gather1(const int* __restrict__ beg,
                          const int* __restrict__ degi,
                          const int* __restrict__ ssrc, const float* __restrict__ dinv,
                          const uint4* __restrict__ hb4, const float* __restrict__ b1,
                          uint4* __restrict__ h1u4, int n) {
    int node = blockIdx.x * 4 + (threadIdx.x >> 6);
    int t = threadIdx.x & 63;
    if (node >= n) return;
    int cnt = degi[node];
    int bg  = beg[node];
    int grp = t >> 4, sub = t & 15;           // 4 edge-groups x 16 dim-lanes

    float a[8] = {0.f,0.f,0.f,0.f,0.f,0.f,0.f,0.f};
    int k = 0;
    for (; k + 16 <= cnt; k += 16) {          // 16 edges: 4 x 1KB wave-loads
        int s[4];
        #pragma unroll
        for (int q = 0; q < 4; ++q) s[q] = ssrc[bg + k + grp * 4 + q];
        float dv[4]; uint4 v[4];
        #pragma unroll
        for (int q = 0; q < 4; ++q) { dv[q] = dinv[s[q]]; v[q] = hb4[(size_t)s[q] * 16 + sub]; }
        #pragma unroll
        for (int q = 0; q < 4; ++q) fma8(a, v[q], dv[q]);
    }
    for (; k < cnt; k += 4) {                 // predicated tail quad
        int idx = k + grp;
        if (idx < cnt) {
            int s = ssrc[bg + idx];
            fma8(a, hb4[(size_t)s * 16 + sub], dinv[s]);
        }
    }

    #pragma unroll
    for (int j = 0; j < 8; ++j) {             // combine the 4 edge-groups
        a[j] += __shfl_xor(a[j], 16);
        a[j] += __shfl_xor(a[j], 32);
    }

    if (grp == 0) {                           // 16 lanes write the 256B row
        uint4 sv = hb4[(size_t)node * 16 + sub];
        float di = dinv[node], dd = di * di;
        float4 bA = ((const float4*)b1)[sub * 2];
        float4 bB = ((const float4*)b1)[sub * 2 + 1];
        float v0 = fmaxf(di * a[0] + dd * bfu(sv.x) + bA.x, 0.f);
        float v1 = fmaxf(di * a[1] + dd * bfh(sv.x) + bA.y, 0.f);
        float v2 = fmaxf(di * a[2] + dd * bfu(sv.y) + bA.z, 0.f);
        float v3 = fmaxf(di * a[3] + dd * bfh(sv.y) + bA.w, 0.f);
        float v4 = fmaxf(di * a[4] + dd * bfu(sv.z) + bB.x, 0.f);
        float v5 = fmaxf(di * a[5] + dd * bfh(sv.z) + bB.y, 0.f);
        float v6 = fmaxf(di * a[6] + dd * bfu(sv.w) + bB.z, 0.f);
        float v7 = fmaxf(di * a[7] + dd * bfh(sv.w) + bB.w, 0.f);
        uint4 o;
        o.x = pack2(v0, v1);
        o.y = pack2(v2, v3);
        o.z = pack2(v4, v5);
        o.w = pack2(v6, v7);
        h1u4[(size_t)node * 16 + sub] = o;    // 4 consecutive rows/wave = 1KB
    }
}

// ==== L5: gemm2: h2b[n,48] = bf16( (h1b @ W2[:, :48]) * dinv[row] ) ========
// 48 cols cover NCLS=47 -> 96B rows, 25% less gather2 traffic.
__global__ __launch_bounds__(256) void k_gemm2_mfma(const short* __restrict__ h1b,
                                                    const short* __restrict__ W2s,
                                                    const float* __restrict__ dinv,
                                                    short* __restrict__ h2b, int n) {
    __shared__ short lw[8192];  // 16 KB: swizzled padded W2
    {
        const uint4* g = (const uint4*)W2s;
        uint4* l = (uint4*)lw;
        for (int i = threadIdx.x; i < 1024; i += 256) l[i] = g[i];
    }
    __syncthreads();

    int wave = threadIdx.x >> 6, lane = threadIdx.x & 63;
    int quad = lane >> 4, lrow = lane & 15;
    long long row0 = (long long)blockIdx.x * 64 + wave * 16;

    f32x4 acc[3];
    #pragma unroll
    for (int nt = 0; nt < 3; ++nt) acc[nt] = (f32x4){0.f, 0.f, 0.f, 0.f};

    const short8* lf = (const short8*)lw;

    #pragma unroll
    for (int kt = 0; kt < 4; ++kt) {
        long long row = row0 + lrow;
        short8 a = (short8){0,0,0,0,0,0,0,0};
        if (row < n) a = *(const short8*)(h1b + row * DHID + kt * 32 + quad * 8);
        #pragma unroll
        for (int nt = 0; nt < 3; ++nt)
            acc[nt] = __builtin_amdgcn_mfma_f32_16x16x32_bf16(a, lf[(kt * 4 + nt) * 64 + lane], acc[nt], 0, 0, 0);
    }
    float dvv[4];
    #pragma unroll
    for (int r = 0; r < 4; ++r) {
        long long row = row0 + quad * 4 + r;
        dvv[r] = (row < n) ? dinv[row] : 0.f;
    }
    #pragma unroll
    for (int nt = 0; nt < 3; ++nt)
        #pragma unroll
        for (int r = 0; r < 4; ++r) {
            long long row = row0 + quad * 4 + r;
            if (row < n) h2b[row * 48 + nt * 16 + lrow] = f2bf(acc[nt][r] * dvv[r]);
        }
}

// ===== L6: gather2 (96B prescaled rows => pure load/add inner loop) ========
__global__ __launch_bounds__(256) void k_gather2(const int* __restrict__ beg,
                          const int* __restrict__ degi,
                          const int* __restrict__ ssrc, const float* __restrict__ dinv,
                          const uint4* __restrict__ h2b6, const float* __restrict__ b2,
                          float* __restrict__ out, int n) {
    int node = blockIdx.x * 4 + (threadIdx.x >> 6);
    int t = threadIdx.x & 63;
    if (node >= n) return;
    int cnt = degi[node];
    int bg  = beg[node];
    int grp = t >> 3, sub = t & 7;            // 8 edge-groups x 8 dim-lanes (sub<6 live)

    float a[8] = {0.f,0.f,0.f,0.f,0.f,0.f,0.f,0.f};
    int k = 0;
    for (; k + 16 <= cnt; k += 16) {          // 16 edges: 2 x 768B wave-loads
        int s0 = ssrc[bg + k + grp], s1 = ssrc[bg + k + 8 + grp];
        if (sub < 6) {
            uint4 v0 = h2b6[(size_t)s0 * 6 + sub];
            uint4 v1 = h2b6[(size_t)s1 * 6 + sub];
            add8(a, v0); add8(a, v1);
        }
    }
    for (; k < cnt; k += 8) {                 // predicated tail octet
        int idx = k + grp;
        if (idx < cnt) {
            int s = ssrc[bg + idx];
            if (sub < 6) add8(a, h2b6[(size_t)s * 6 + sub]);
        }
    }
    if (grp == 0 && sub < 6) add8(a, h2b6[(size_t)node * 6 + sub]);   // self

    #pragma unroll
    for (int j = 0; j < 8; ++j) {             // combine the 8 edge-groups
        a[j] += __shfl_xor(a[j], 8);
        a[j] += __shfl_xor(a[j], 16);
        a[j] += __shfl_xor(a[j], 32);
    }

    if (grp == 0) {
        float di = dinv[node];
        #pragma unroll
        for (int j = 0; j < 8; ++j) {
            int c = sub * 8 + j;
            if (c < NCLS) out[(size_t)node * NCLS + c] = di * a[j] + b2[c];
        }
    }
}

// ===========================================================================
extern "C" void kernel_launch(void* const* d_in, const int* in_sizes, int n_in,
                              void* d_out, int out_size, void* d_ws, size_t ws_size,
                              hipStream_t stream) {
    const float* x  = (const float*)d_in[0];
    const int*   ei = (const int*)d_in[1];
    const float* W1 = (const float*)d_in[2];
    const float* b1 = (const float*)d_in[3];
    const float* W2 = (const float*)d_in[4];
    const float* b2 = (const float*)d_in[5];

    const int n = in_sizes[0] / DIN;   // 100000
    const int E = in_sizes[1] / 2;     // 1600000
    const int* src = ei;
    const int* dst = ei + E;
    float* out = (float*)d_out;

    const int NB = (n + BNODES - 1) >> BSHIFT;   // 196 buckets
    const int npad = NB << BSHIFT;               // 100352 (bucket-padded)

    // workspace layout (~47 MB)
    char* w = (char*)d_ws;
    int*   degc = (int*)w;                     w += (size_t)npad * 4;         // zeroed
    int*   btot = (int*)w;                     w += (size_t)256 * 4;          // zeroed
    int*   degi = (int*)w;                     w += (size_t)n * 4;
    int*   beg  = (int*)w;                     w += (size_t)n * 4;
    int*   cur  = (int*)w;                     w += (size_t)n * 4;
    float* dinv = (float*)w;                   w += (size_t)n * 4;
    short* W1s  = (short*)w;                   w += (size_t)32768 * 2;        // 64 KB
    short* W2s  = (short*)w;                   w += (size_t)8192 * 2;         // 16 KB
    int*   bbuf = (int*)w;                     w += (size_t)E * 4;            // CSR src
    short* hb   = (short*)w;                   w += (size_t)n * DHID * 2;     // bf16 x@W1
    short* h1b  = (short*)w;                   w += (size_t)n * DHID * 2;     // bf16 relu layer1
    short* h2b  = (short*)w;                   w += (size_t)n * 48 * 2;       // bf16 (h1@W2)*dinv, 48 cols

    const int ndeg = (E + 1023) / 1024;          // 1563 degree blocks (4 edges/thr)
    const int nsc  = ((E >> 2) + 255) / 256;     // 1563 scatter blocks

    // zero degc + btot (contiguous)
    hipMemsetAsync(degc, 0, ((size_t)npad + 256) * 4, stream);
    // L1: weight swizzles + degree/bucket atomics
    k_prep<<<20 + ndeg, 256, 0, stream>>>(W1, W2, W1s, W2s, dst, degc, btot, E);
    // L2: CSR offsets (scan) || gemm1 (hides it)
    k_build_gemm1<<<NB + (n + 127) / 128, 256, 0, stream>>>(btot, degc, degi, beg, cur,
                                                            dinv, n, NB, x, W1s, hb);
    // L3: slot-atomic scatter
    k_scatter<<<nsc, 256, 0, stream>>>(src, dst, cur, bbuf, E);
    // L4: gather1 (fused bias+self+relu, bf16 out)
    k_gather1<<<(n + 3) / 4, 256, 0, stream>>>(beg, degi, bbuf, dinv,
                                               (const uint4*)hb, b1,
                                               (uint4*)h1b, n);
    // L5: gemm2 (prescales 48-col h2b by dinv[row])
    k_gemm2_mfma<<<(n + 63) / 64, 256, 0, stream>>>(h1b, W2s, dinv, h2b, n);
    // L6: gather2 (fused bias+self)
    k_gather2<<<(n + 3) / 4, 256, 0, stream>>>(beg, degi, bbuf, dinv,
                                               (const uint4*)h2b, b2, out, n);
}

// Round 6
// 367.806 us; speedup vs baseline: 1.4828x; 1.4828x over previous
//
#include <hip/hip_runtime.h>
#include <hip/hip_bf16.h>

#define DIN 256
#define DHID 128
#define NCLS 47
#define BSHIFT 9                 // bucket = dst >> 9  (512 nodes/bucket)
#define BNODES 512
#define NPART 1024               // edge partitions (chunk = 1563)
#define BCAPS 9216               // per-bucket cap (lambda 8192 + 11 sigma)
#define CHUNKE 1600              // per-partition LDS stage cap (chunk = 1563)

typedef __attribute__((ext_vector_type(8))) short short8;   // 8 bf16 (4 VGPRs)
typedef __attribute__((ext_vector_type(4))) float f32x4;

__device__ __forceinline__ short f2bf(float f) {
    __bf16 b = (__bf16)f;                 // RNE convert
    return __builtin_bit_cast(short, b);
}
__device__ __forceinline__ float bfu(unsigned int u) {   // low 16 bits = bf16
    return __uint_as_float(u << 16);
}
__device__ __forceinline__ float bfh(unsigned int u) {   // high 16 bits = bf16
    return __uint_as_float(u & 0xffff0000u);
}
__device__ __forceinline__ unsigned int pack2(float lo, float hi) {
    return (unsigned int)(unsigned short)f2bf(lo)
         | ((unsigned int)(unsigned short)f2bf(hi) << 16);
}
// a[j] += row[j] (8 bf16 in one uint4)
__device__ __forceinline__ void add8(float* a, uint4 v) {
    a[0] += bfu(v.x); a[1] += bfh(v.x);
    a[2] += bfu(v.y); a[3] += bfh(v.y);
    a[4] += bfu(v.z); a[5] += bfh(v.z);
    a[6] += bfu(v.w); a[7] += bfh(v.w);
}
// a[j] += d * row[j]
__device__ __forceinline__ void fma8(float* a, uint4 v, float d) {
    a[0] += d * bfu(v.x); a[1] += d * bfh(v.x);
    a[2] += d * bfu(v.y); a[3] += d * bfh(v.y);
    a[4] += d * bfu(v.z); a[5] += d * bfh(v.z);
    a[6] += d * bfu(v.w); a[7] += d * bfh(v.w);
}

// ===== L1: weight swizzles + per-partition histogram (disjoint blocks) =====
// ghist TRANSPOSED: ghist[bucket * NPART + part]. 1044 blocks (high TLP).
__global__ __launch_bounds__(256) void k_prep_hist(const float* __restrict__ W1,
                                                   const float* __restrict__ W2,
                                                   short* __restrict__ W1s,
                                                   short* __restrict__ W2s,
                                                   const int* __restrict__ dst,
                                                   int* __restrict__ ghist,
                                                   int E, int NB, int chunk) {
    __shared__ int lh[256];
    int blk = blockIdx.x, t = threadIdx.x;
    if (blk < 16) {                      // W1 -> B-fragment swizzle
        int tid = blk * 256 + t;         // 0..4095
        int frag = tid >> 6, lane = tid & 63;
        int kt = frag >> 3, nt = frag & 7;
        int quad = lane >> 4, col = lane & 15;
        #pragma unroll
        for (int j = 0; j < 8; ++j) {
            int k = kt * 32 + quad * 8 + j;
            W1s[(size_t)tid * 8 + j] = f2bf(W1[k * DHID + nt * 16 + col]);
        }
    } else if (blk < 20) {               // W2 -> B-fragment swizzle (pad N to 64)
        int tid = (blk - 16) * 256 + t;  // 0..1023
        int frag = tid >> 6, lane = tid & 63;
        int kt = frag >> 2, nt = frag & 3;
        int quad = lane >> 4, col = lane & 15;
        int c = nt * 16 + col;
        #pragma unroll
        for (int j = 0; j < 8; ++j) {
            int k = kt * 32 + quad * 8 + j;
            float v = (c < NCLS) ? W2[k * NCLS + c] : 0.0f;
            W2s[(size_t)tid * 8 + j] = f2bf(v);
        }
    } else {                             // per-partition bucket histogram
        int p = blk - 20;
        for (int i = t; i < NB; i += 256) lh[i] = 0;
        __syncthreads();
        int lo = p * chunk, hi = min(E, lo + chunk);
        for (int i = lo + t; i < hi; i += 256)
            atomicAdd(&lh[dst[i] >> BSHIFT], 1);
        __syncthreads();
        for (int i = t; i < NB; i += 256) ghist[(size_t)i * NPART + p] = lh[i];
    }
}

// ===== L2: column scan: goff[b][p] = exclusive prefix over parts; btot =====
// 196 blocks x 256 threads, int4 loads of the contiguous transposed row.
__global__ __launch_bounds__(256) void k_colscan(const int* __restrict__ ghist,
                                                 int* __restrict__ goff,
                                                 int* __restrict__ btot) {
    __shared__ int wsum[4];
    int b = blockIdx.x, t = threadIdx.x;
    int4 v = ((const int4*)(ghist + (size_t)b * NPART))[t];
    int s = v.x + v.y + v.z + v.w;
    int incl = s;
    int lane = t & 63, w = t >> 6;
    #pragma unroll
    for (int off = 1; off < 64; off <<= 1) {
        int u = __shfl_up(incl, off, 64);
        if (lane >= off) incl += u;
    }
    if (lane == 63) wsum[w] = incl;
    __syncthreads();
    int wadd = 0;
    for (int i = 0; i < w; ++i) wadd += wsum[i];
    int ex = wadd + incl - s;
    int4 o;
    o.x = ex; o.y = ex + v.x; o.z = o.y + v.y; o.w = o.z + v.z;
    ((int4*)(goff + (size_t)b * NPART))[t] = o;
    if (t == 255) btot[b] = wadd + incl;
}

// 256-thread exclusive scan of btot -> lbase[0..255]; ends synced
__device__ __forceinline__ void scan_btot(const int* __restrict__ btot, int NB,
                                          int* lbase, int* wsum) {
    int t = threadIdx.x;
    int v = (t < NB) ? btot[t] : 0;
    int incl = v;
    int lane = t & 63, w = t >> 6;
    #pragma unroll
    for (int off = 1; off < 64; off <<= 1) {
        int u = __shfl_up(incl, off, 64);
        if (lane >= off) incl += u;
    }
    if (lane == 63) wsum[w] = incl;
    __syncthreads();
    int wadd = 0;
    for (int i = 0; i < w; ++i) wadd += wsum[i];
    lbase[t] = wadd + incl - v;   // exclusive
    __syncthreads();
}

// ===== L3: scatter (1024 light blocks) PARALLEL gemm1 (LDS-free) ===========
// scatter: LDS-staged, dest-ordered global writes (no write amplification).
// gemm1 reads swizzled W1 straight from L2 (50 MB coalesced ~ 1.5 us) so the
// scatter blocks keep a small LDS footprint -> high occupancy.
__global__ __launch_bounds__(256) void k_scatter_gemm1(const int* __restrict__ src,
                                                       const int* __restrict__ dst,
                                                       const int* __restrict__ ghist,
                                                       const int* __restrict__ goff,
                                                       const int* __restrict__ btot,
                                                       unsigned int* __restrict__ bbuf,
                                                       int E, int NB, int chunk,
                                                       const float* __restrict__ x,
                                                       const short* __restrict__ W1s,
                                                       short* __restrict__ hb, int n) {
    __shared__ unsigned int stage[CHUNKE];   // 6.4 KB
    __shared__ int sdest[CHUNKE];            // 6.4 KB
    __shared__ int lcur[256];
    __shared__ int gdst[256];
    __shared__ int wsum[4];

    int blk = blockIdx.x, t = threadIdx.x;

    if (blk < NPART) {
        int p = blk;
        scan_btot(btot, NB, gdst, wsum);     // gdst = global bucket base

        int mine = (t < NB) ? ghist[(size_t)t * NPART + p] : 0;
        int incl = mine;
        int lane = t & 63, w = t >> 6;
        #pragma unroll
        for (int off = 1; off < 64; off <<= 1) {
            int u = __shfl_up(incl, off, 64);
            if (lane >= off) incl += u;
        }
        if (lane == 63) wsum[w] = incl;
        __syncthreads();
        int wadd = 0;
        for (int i = 0; i < w; ++i) wadd += wsum[i];
        int ex = wadd + incl - mine;         // local exclusive prefix
        lcur[t] = ex;
        if (t < NB) gdst[t] += goff[(size_t)t * NPART + p] - ex;
        __syncthreads();

        int lo = p * chunk, hi = min(E, lo + chunk), cnt = hi - lo;
        for (int i = lo + t; i < hi; i += 256) {
            int d = dst[i];
            int b = d >> BSHIFT;
            int slot = atomicAdd(&lcur[b], 1);
            stage[slot] = (unsigned int)src[i] | ((unsigned int)(d & (BNODES - 1)) << 17);
            sdest[slot] = gdst[b] + slot;
        }
        __syncthreads();
        for (int i = t; i < cnt; i += 256)   // consecutive i -> consecutive dest
            bbuf[sdest[i]] = stage[i];
    } else {
        // ---------------- gemm1 path: hb = bf16(x @ W1), W1s from L2 -------
        int bid = blk - NPART;
        int wave = t >> 6, lane = t & 63;
        int quad = lane >> 4, lrow = lane & 15;
        long long rowbase = (long long)bid * 128 + wave * 32;

        f32x4 acc[2][8];
        #pragma unroll
        for (int rt = 0; rt < 2; ++rt)
            #pragma unroll
            for (int nt = 0; nt < 8; ++nt) acc[rt][nt] = (f32x4){0.f, 0.f, 0.f, 0.f};

        const short8* lf = (const short8*)W1s;

        #pragma unroll
        for (int kt = 0; kt < 8; ++kt) {
            int k0 = kt * 32 + quad * 8;
            short8 a[2];
            #pragma unroll
            for (int rt = 0; rt < 2; ++rt) {
                long long row = rowbase + rt * 16 + lrow;
                float4 v0 = {0.f,0.f,0.f,0.f}, v1 = {0.f,0.f,0.f,0.f};
                if (row < n) {
                    const float* xp = x + row * DIN + k0;
                    v0 = *(const float4*)xp;
                    v1 = *(const float4*)(xp + 4);
                }
                short8 av;
                av[0] = f2bf(v0.x); av[1] = f2bf(v0.y); av[2] = f2bf(v0.z); av[3] = f2bf(v0.w);
                av[4] = f2bf(v1.x); av[5] = f2bf(v1.y); av[6] = f2bf(v1.z); av[7] = f2bf(v1.w);
                a[rt] = av;
            }
            #pragma unroll
            for (int nt = 0; nt < 8; ++nt) {
                short8 b = lf[(kt * 8 + nt) * 64 + lane];
                acc[0][nt] = __builtin_amdgcn_mfma_f32_16x16x32_bf16(a[0], b, acc[0][nt], 0, 0, 0);
                acc[1][nt] = __builtin_amdgcn_mfma_f32_16x16x32_bf16(a[1], b, acc[1][nt], 0, 0, 0);
            }
        }
        #pragma unroll
        for (int rt = 0; rt < 2; ++rt)
            #pragma unroll
            for (int nt = 0; nt < 8; ++nt)
                #pragma unroll
                for (int r = 0; r < 4; ++r) {
                    long long row = rowbase + rt * 16 + quad * 4 + r;
                    if (row < n) hb[row * DHID + nt * 16 + lrow] = f2bf(acc[rt][nt][r]);
                }
    }
}

// ===== L4: per-bucket counting sort, 512 threads (8 waves) per bucket ======
__global__ __launch_bounds__(512) void k_bsort(const int* __restrict__ btot,
                                               unsigned int* __restrict__ bbuf,
                                               int* __restrict__ degi,
                                               int* __restrict__ beg,
                                               float* __restrict__ dinv, int n, int NB) {
    __shared__ unsigned int stage[BCAPS];    // 36 KB
    __shared__ int hist[BNODES];
    __shared__ int cur[BNODES];
    __shared__ int lbase[256];
    __shared__ int wsum[4];

    int b = blockIdx.x, t = threadIdx.x;

    // 512-thread-safe scan of btot (work on t<256, barriers outside guards)
    if (t < 256) {
        int v = (t < NB) ? btot[t] : 0;
        int incl = v;
        int lane = t & 63, w = t >> 6;
        #pragma unroll
        for (int off = 1; off < 64; off <<= 1) {
            int u = __shfl_up(incl, off, 64);
            if (lane >= off) incl += u;
        }
        if (lane == 63) wsum[w] = incl;
        lbase[t] = v;   // stash v
    }
    __syncthreads();
    if (t < 256) {
        int v = lbase[t];
        int incl = v;
        int lane = t & 63, w = t >> 6;
        #pragma unroll
        for (int off = 1; off < 64; off <<= 1) {
            int u = __shfl_up(incl, off, 64);
            if (lane >= off) incl += u;
        }
        int wadd = 0;
        for (int i = 0; i < w; ++i) wadd += wsum[i];
        lbase[t] = wadd + incl - v;
    }
    hist[t] = 0;                 // 512 counters, 512 threads
    __syncthreads();

    int cnt = min(btot[b], BCAPS);
    int gbase = lbase[b];
    int node0 = b << BSHIFT;

    for (int i = t; i < cnt; i += 512) {
        unsigned int p = bbuf[gbase + i];
        stage[i] = p;
        atomicAdd(&hist[p >> 17], 1);
    }
    __syncthreads();

    // exclusive scan of 512 counters: thread t<256 owns pair (2t, 2t+1)
    int v0 = 0, v1 = 0, ex = 0;
    if (t < 256) {
        v0 = hist[2 * t]; v1 = hist[2 * t + 1];
        int s = v0 + v1;
        int incl = s;
        int lane = t & 63, w = t >> 6;
        #pragma unroll
        for (int off = 1; off < 64; off <<= 1) {
            int u = __shfl_up(incl, off, 64);
            if (lane >= off) incl += u;
        }
        if (lane == 63) wsum[w] = incl;
        ex = incl - s;   // partial (wave-local incl); add wadd after sync
    }
    __syncthreads();
    if (t < 256) {
        int lane = t & 63, w = t >> 6;
        (void)lane;
        int wadd = 0;
        for (int i = 0; i < w; ++i) wadd += wsum[i];
        ex += wadd;
        cur[2 * t] = ex;
        cur[2 * t + 1] = ex + v0;
        int nodeA = node0 + 2 * t, nodeB = node0 + 2 * t + 1;
        if (nodeA < n) {
            degi[nodeA] = v0;
            beg[nodeA]  = gbase + ex;
            dinv[nodeA] = rsqrtf((float)(v0 + 1));
        }
        if (nodeB < n) {
            degi[nodeB] = v1;
            beg[nodeB]  = gbase + ex + v0;
            dinv[nodeB] = rsqrtf((float)(v1 + 1));
        }
    }
    __syncthreads();

    for (int i = t; i < cnt; i += 512) {
        unsigned int p = stage[i];
        int slot = atomicAdd(&cur[p >> 17], 1);
        bbuf[gbase + slot] = p & 0x1FFFFu;
    }
}

// ===== L5: gather1 — proven round-1 interleave, per-edge dinv ==============
// wave = 1 node; 4 edge-groups x 16 dim-lanes; 4 uint4 gathers in flight.
__global__ __launch_bounds__(256) void k_gather1(const int* __restrict__ beg,
                          const int* __restrict__ degi,
                          const int* __restrict__ ssrc, const float* __restrict__ dinv,
                          const uint4* __restrict__ hb4, const float* __restrict__ b1,
                          uint4* __restrict__ h1u4, int n) {
    int node = blockIdx.x * 4 + (threadIdx.x >> 6);
    int t = threadIdx.x & 63;
    if (node >= n) return;
    int cnt = degi[node];
    int bg  = beg[node];
    int grp = t >> 4, sub = t & 15;           // 4 edge-groups x 16 dim-lanes

    float a[8] = {0.f,0.f,0.f,0.f,0.f,0.f,0.f,0.f};
    int k = 0;
    for (; k + 16 <= cnt; k += 16) {          // 16 edges: 4 x 1KB wave-loads
        int s[4];
        #pragma unroll
        for (int q = 0; q < 4; ++q) s[q] = ssrc[bg + k + grp * 4 + q];
        float dv[4]; uint4 v[4];
        #pragma unroll
        for (int q = 0; q < 4; ++q) { dv[q] = dinv[s[q]]; v[q] = hb4[(size_t)s[q] * 16 + sub]; }
        #pragma unroll
        for (int q = 0; q < 4; ++q) fma8(a, v[q], dv[q]);
    }
    for (; k < cnt; k += 4) {                 // predicated tail quad
        int idx = k + grp;
        if (idx < cnt) {
            int s = ssrc[bg + idx];
            fma8(a, hb4[(size_t)s * 16 + sub], dinv[s]);
        }
    }

    #pragma unroll
    for (int j = 0; j < 8; ++j) {             // combine the 4 edge-groups
        a[j] += __shfl_xor(a[j], 16);
        a[j] += __shfl_xor(a[j], 32);
    }

    if (grp == 0) {                           // 16 lanes write the 256B row
        uint4 sv = hb4[(size_t)node * 16 + sub];
        float di = dinv[node], dd = di * di;
        float4 bA = ((const float4*)b1)[sub * 2];
        float4 bB = ((const float4*)b1)[sub * 2 + 1];
        float v0 = fmaxf(di * a[0] + dd * bfu(sv.x) + bA.x, 0.f);
        float v1 = fmaxf(di * a[1] + dd * bfh(sv.x) + bA.y, 0.f);
        float v2 = fmaxf(di * a[2] + dd * bfu(sv.y) + bA.z, 0.f);
        float v3 = fmaxf(di * a[3] + dd * bfh(sv.y) + bA.w, 0.f);
        float v4 = fmaxf(di * a[4] + dd * bfu(sv.z) + bB.x, 0.f);
        float v5 = fmaxf(di * a[5] + dd * bfh(sv.z) + bB.y, 0.f);
        float v6 = fmaxf(di * a[6] + dd * bfu(sv.w) + bB.z, 0.f);
        float v7 = fmaxf(di * a[7] + dd * bfh(sv.w) + bB.w, 0.f);
        uint4 o;
        o.x = pack2(v0, v1);
        o.y = pack2(v2, v3);
        o.z = pack2(v4, v5);
        o.w = pack2(v6, v7);
        h1u4[(size_t)node * 16 + sub] = o;    // 4 consecutive rows/wave = 1KB
    }
}

// ==== L6: gemm2: h2b[n,48] = bf16( (h1b @ W2[:, :48]) * dinv[row] ) ========
// 48 cols cover NCLS=47 -> 96B rows, 25% less gather2 traffic.
__global__ __launch_bounds__(256) void k_gemm2_mfma(const short* __restrict__ h1b,
                                                    const short* __restrict__ W2s,
                                                    const float* __restrict__ dinv,
                                                    short* __restrict__ h2b, int n) {
    __shared__ short lw[8192];  // 16 KB: swizzled padded W2
    {
        const uint4* g = (const uint4*)W2s;
        uint4* l = (uint4*)lw;
        for (int i = threadIdx.x; i < 1024; i += 256) l[i] = g[i];
    }
    __syncthreads();

    int wave = threadIdx.x >> 6, lane = threadIdx.x & 63;
    int quad = lane >> 4, lrow = lane & 15;
    long long row0 = (long long)blockIdx.x * 64 + wave * 16;

    f32x4 acc[3];
    #pragma unroll
    for (int nt = 0; nt < 3; ++nt) acc[nt] = (f32x4){0.f, 0.f, 0.f, 0.f};

    const short8* lf = (const short8*)lw;

    #pragma unroll
    for (int kt = 0; kt < 4; ++kt) {
        long long row = row0 + lrow;
        short8 a = (short8){0,0,0,0,0,0,0,0};
        if (row < n) a = *(const short8*)(h1b + row * DHID + kt * 32 + quad * 8);
        #pragma unroll
        for (int nt = 0; nt < 3; ++nt)
            acc[nt] = __builtin_amdgcn_mfma_f32_16x16x32_bf16(a, lf[(kt * 4 + nt) * 64 + lane], acc[nt], 0, 0, 0);
    }
    float dvv[4];
    #pragma unroll
    for (int r = 0; r < 4; ++r) {
        long long row = row0 + quad * 4 + r;
        dvv[r] = (row < n) ? dinv[row] : 0.f;
    }
    #pragma unroll
    for (int nt = 0; nt < 3; ++nt)
        #pragma unroll
        for (int r = 0; r < 4; ++r) {
            long long row = row0 + quad * 4 + r;
            if (row < n) h2b[row * 48 + nt * 16 + lrow] = f2bf(acc[nt][r] * dvv[r]);
        }
}

// ===== L7: gather2 (96B prescaled rows => pure load/add inner loop) ========
__global__ __launch_bounds__(256) void k_gather2(const int* __restrict__ beg,
                          const int* __restrict__ degi,
                          const int* __restrict__ ssrc, const float* __restrict__ dinv,
                          const uint4* __restrict__ h2b6, const float* __restrict__ b2,
                          float* __restrict__ out, int n) {
    int node = blockIdx.x * 4 + (threadIdx.x >> 6);
    int t = threadIdx.x & 63;
    if (node >= n) return;
    int cnt = degi[node];
    int bg  = beg[node];
    int grp = t >> 3, sub = t & 7;            // 8 edge-groups x 8 dim-lanes (sub<6 live)

    float a[8] = {0.f,0.f,0.f,0.f,0.f,0.f,0.f,0.f};
    int k = 0;
    for (; k + 16 <= cnt; k += 16) {          // 16 edges: 2 x 768B wave-loads
        int s0 = ssrc[bg + k + grp], s1 = ssrc[bg + k + 8 + grp];
        if (sub < 6) {
            uint4 v0 = h2b6[(size_t)s0 * 6 + sub];
            uint4 v1 = h2b6[(size_t)s1 * 6 + sub];
            add8(a, v0); add8(a, v1);
        }
    }
    for (; k < cnt; k += 8) {                 // predicated tail octet
        int idx = k + grp;
        if (idx < cnt) {
            int s = ssrc[bg + idx];
            if (sub < 6) add8(a, h2b6[(size_t)s * 6 + sub]);
        }
    }
    if (grp == 0 && sub < 6) add8(a, h2b6[(size_t)node * 6 + sub]);   // self

    #pragma unroll
    for (int j = 0; j < 8; ++j) {             // combine the 8 edge-groups
        a[j] += __shfl_xor(a[j], 8);
        a[j] += __shfl_xor(a[j], 16);
        a[j] += __shfl_xor(a[j], 32);
    }

    if (grp == 0) {
        float di = dinv[node];
        #pragma unroll
        for (int j = 0; j < 8; ++j) {
            int c = sub * 8 + j;
            if (c < NCLS) out[(size_t)node * NCLS + c] = di * a[j] + b2[c];
        }
    }
}

// ===========================================================================
extern "C" void kernel_launch(void* const* d_in, const int* in_sizes, int n_in,
                              void* d_out, int out_size, void* d_ws, size_t ws_size,
                              hipStream_t stream) {
    const float* x  = (const float*)d_in[0];
    const int*   ei = (const int*)d_in[1];
    const float* W1 = (const float*)d_in[2];
    const float* b1 = (const float*)d_in[3];
    const float* W2 = (const float*)d_in[4];
    const float* b2 = (const float*)d_in[5];

    const int n = in_sizes[0] / DIN;   // 100000
    const int E = in_sizes[1] / 2;     // 1600000
    const int* src = ei;
    const int* dst = ei + E;
    float* out = (float*)d_out;

    const int NB = (n + BNODES - 1) >> BSHIFT;   // 196 buckets
    const int chunk = (E + NPART - 1) / NPART;   // 1563

    // workspace layout (~49 MB)
    char* w = (char*)d_ws;
    int*   ghist = (int*)w;                    w += (size_t)NB * NPART * 4;   // 800 KB (transposed)
    int*   goff  = (int*)w;                    w += (size_t)NB * NPART * 4;   // 800 KB
    int*   btot  = (int*)w;                    w += ((size_t)256 * 4);
    int*   degi  = (int*)w;                    w += (size_t)n * 4;
    int*   beg   = (int*)w;                    w += (size_t)n * 4;
    float* dinv  = (float*)w;                  w += (size_t)n * 4;
    short* W1s   = (short*)w;                  w += (size_t)32768 * 2;        // 64 KB
    short* W2s   = (short*)w;                  w += (size_t)8192 * 2;         // 16 KB
    unsigned int* bbuf = (unsigned int*)w;     w += (size_t)E * 4;            // CSR src
    short* hb    = (short*)w;                  w += (size_t)n * DHID * 2;     // bf16 x@W1
    short* h1b   = (short*)w;                  w += (size_t)n * DHID * 2;     // bf16 relu layer1
    short* h2b   = (short*)w;                  w += (size_t)n * 48 * 2;       // bf16 (h1@W2)*dinv, 48 cols

    // L1: weight swizzles + per-partition histogram (1044 blocks)
    k_prep_hist<<<20 + NPART, 256, 0, stream>>>(W1, W2, W1s, W2s, dst, ghist, E, NB, chunk);
    // L2: column scan -> goff, btot (196 blocks, int4)
    k_colscan<<<NB, 256, 0, stream>>>(ghist, goff, btot);
    // L3: scatter (1024 light blocks) || gemm1 (LDS-free, hides under it)
    k_scatter_gemm1<<<NPART + (n + 127) / 128, 256, 0, stream>>>(src, dst, ghist, goff, btot,
                                                                 bbuf, E, NB, chunk,
                                                                 x, W1s, hb, n);
    // L4: per-bucket counting sort (512 threads/block)
    k_bsort<<<NB, 512, 0, stream>>>(btot, bbuf, degi, beg, dinv, n, NB);
    // L5: gather1 (fused bias+self+relu, bf16 out)
    k_gather1<<<(n + 3) / 4, 256, 0, stream>>>(beg, degi, (const int*)bbuf, dinv,
                                               (const uint4*)hb, b1,
                                               (uint4*)h1b, n);
    // L6: gemm2 (prescales 48-col h2b by dinv[row])
    k_gemm2_mfma<<<(n + 63) / 64, 256, 0, stream>>>(h1b, W2s, dinv, h2b, n);
    // L7: gather2 (fused bias+self)
    k_gather2<<<(n + 3) / 4, 256, 0, stream>>>(beg, degi, (const int*)bbuf, dinv,
                                               (const uint4*)h2b, b2, out, n);
}

// Round 7
// 353.853 us; speedup vs baseline: 1.5413x; 1.0394x over previous
//
#include <hip/hip_runtime.h>
#include <hip/hip_bf16.h>

#define DIN 256
#define DHID 128
#define NCLS 47
#define BSHIFT 9                 // bucket = dst >> 9  (512 nodes/bucket)
#define BNODES 512
#define NPART 1024               // edge partitions (chunk = 1563)
#define BCAPS 9216               // per-bucket cap (lambda 8192 + 11 sigma)
#define CHUNKE 1600              // per-partition LDS stage cap (chunk = 1563)

typedef __attribute__((ext_vector_type(8))) short short8;   // 8 bf16 (4 VGPRs)
typedef __attribute__((ext_vector_type(4))) float f32x4;

__device__ __forceinline__ short f2bf(float f) {
    __bf16 b = (__bf16)f;                 // RNE convert
    return __builtin_bit_cast(short, b);
}
__device__ __forceinline__ float bfu(unsigned int u) {   // low 16 bits = bf16
    return __uint_as_float(u << 16);
}
__device__ __forceinline__ float bfh(unsigned int u) {   // high 16 bits = bf16
    return __uint_as_float(u & 0xffff0000u);
}
__device__ __forceinline__ unsigned int pack2(float lo, float hi) {
    return (unsigned int)(unsigned short)f2bf(lo)
         | ((unsigned int)(unsigned short)f2bf(hi) << 16);
}
// a[j] += row[j] (8 bf16 in one uint4)
__device__ __forceinline__ void add8(float* a, uint4 v) {
    a[0] += bfu(v.x); a[1] += bfh(v.x);
    a[2] += bfu(v.y); a[3] += bfh(v.y);
    a[4] += bfu(v.z); a[5] += bfh(v.z);
    a[6] += bfu(v.w); a[7] += bfh(v.w);
}
// a[j] += d * row[j]
__device__ __forceinline__ void fma8(float* a, uint4 v, float d) {
    a[0] += d * bfu(v.x); a[1] += d * bfh(v.x);
    a[2] += d * bfu(v.y); a[3] += d * bfh(v.y);
    a[4] += d * bfu(v.z); a[5] += d * bfh(v.z);
    a[6] += d * bfu(v.w); a[7] += d * bfh(v.w);
}

// ===== L1: weight swizzles + per-partition histogram (disjoint blocks) =====
// ghist TRANSPOSED: ghist[bucket * NPART + part]. 1044 blocks (high TLP).
__global__ __launch_bounds__(256) void k_prep_hist(const float* __restrict__ W1,
                                                   const float* __restrict__ W2,
                                                   short* __restrict__ W1s,
                                                   short* __restrict__ W2s,
                                                   const int* __restrict__ dst,
                                                   int* __restrict__ ghist,
                                                   int E, int NB, int chunk) {
    __shared__ int lh[256];
    int blk = blockIdx.x, t = threadIdx.x;
    if (blk < 16) {                      // W1 -> B-fragment swizzle
        int tid = blk * 256 + t;         // 0..4095
        int frag = tid >> 6, lane = tid & 63;
        int kt = frag >> 3, nt = frag & 7;
        int quad = lane >> 4, col = lane & 15;
        #pragma unroll
        for (int j = 0; j < 8; ++j) {
            int k = kt * 32 + quad * 8 + j;
            W1s[(size_t)tid * 8 + j] = f2bf(W1[k * DHID + nt * 16 + col]);
        }
    } else if (blk < 20) {               // W2 -> B-fragment swizzle (pad N to 64)
        int tid = (blk - 16) * 256 + t;  // 0..1023
        int frag = tid >> 6, lane = tid & 63;
        int kt = frag >> 2, nt = frag & 3;
        int quad = lane >> 4, col = lane & 15;
        int c = nt * 16 + col;
        #pragma unroll
        for (int j = 0; j < 8; ++j) {
            int k = kt * 32 + quad * 8 + j;
            float v = (c < NCLS) ? W2[k * NCLS + c] : 0.0f;
            W2s[(size_t)tid * 8 + j] = f2bf(v);
        }
    } else {                             // per-partition bucket histogram
        int p = blk - 20;
        for (int i = t; i < NB; i += 256) lh[i] = 0;
        __syncthreads();
        int lo = p * chunk, hi = min(E, lo + chunk);
        for (int i = lo + t; i < hi; i += 256)
            atomicAdd(&lh[dst[i] >> BSHIFT], 1);
        __syncthreads();
        for (int i = t; i < NB; i += 256) ghist[(size_t)i * NPART + p] = lh[i];
    }
}

// ===== L2: column scan: goff[b][p] = exclusive prefix over parts; btot =====
// 196 blocks x 256 threads, int4 loads of the contiguous transposed row.
__global__ __launch_bounds__(256) void k_colscan(const int* __restrict__ ghist,
                                                 int* __restrict__ goff,
                                                 int* __restrict__ btot) {
    __shared__ int wsum[4];
    int b = blockIdx.x, t = threadIdx.x;
    int4 v = ((const int4*)(ghist + (size_t)b * NPART))[t];
    int s = v.x + v.y + v.z + v.w;
    int incl = s;
    int lane = t & 63, w = t >> 6;
    #pragma unroll
    for (int off = 1; off < 64; off <<= 1) {
        int u = __shfl_up(incl, off, 64);
        if (lane >= off) incl += u;
    }
    if (lane == 63) wsum[w] = incl;
    __syncthreads();
    int wadd = 0;
    for (int i = 0; i < w; ++i) wadd += wsum[i];
    int ex = wadd + incl - s;
    int4 o;
    o.x = ex; o.y = ex + v.x; o.z = o.y + v.y; o.w = o.z + v.z;
    ((int4*)(goff + (size_t)b * NPART))[t] = o;
    if (t == 255) btot[b] = wadd + incl;
}

// 256-thread exclusive scan of btot -> lbase[0..255]; ends synced
__device__ __forceinline__ void scan_btot(const int* __restrict__ btot, int NB,
                                          int* lbase, int* wsum) {
    int t = threadIdx.x;
    int v = (t < NB) ? btot[t] : 0;
    int incl = v;
    int lane = t & 63, w = t >> 6;
    #pragma unroll
    for (int off = 1; off < 64; off <<= 1) {
        int u = __shfl_up(incl, off, 64);
        if (lane >= off) incl += u;
    }
    if (lane == 63) wsum[w] = incl;
    __syncthreads();
    int wadd = 0;
    for (int i = 0; i < w; ++i) wadd += wsum[i];
    lbase[t] = wadd + incl - v;   // exclusive
    __syncthreads();
}

// ===== L3: scatter (standalone, light: 15 KB LDS, 1024 blocks) =============
// LDS-staged, dest-ordered global writes (no write amplification).
__global__ __launch_bounds__(256) void k_scatter(const int* __restrict__ src,
                                                 const int* __restrict__ dst,
                                                 const int* __restrict__ ghist,
                                                 const int* __restrict__ goff,
                                                 const int* __restrict__ btot,
                                                 unsigned int* __restrict__ bbuf,
                                                 int E, int NB, int chunk) {
    __shared__ unsigned int stage[CHUNKE];   // 6.4 KB
    __shared__ int sdest[CHUNKE];            // 6.4 KB
    __shared__ int lcur[256];
    __shared__ int gdst[256];
    __shared__ int wsum[4];

    int p = blockIdx.x, t = threadIdx.x;
    scan_btot(btot, NB, gdst, wsum);         // gdst = global bucket base

    int mine = (t < NB) ? ghist[(size_t)t * NPART + p] : 0;
    int incl = mine;
    int lane = t & 63, w = t >> 6;
    #pragma unroll
    for (int off = 1; off < 64; off <<= 1) {
        int u = __shfl_up(incl, off, 64);
        if (lane >= off) incl += u;
    }
    if (lane == 63) wsum[w] = incl;
    __syncthreads();
    int wadd = 0;
    for (int i = 0; i < w; ++i) wadd += wsum[i];
    int ex = wadd + incl - mine;             // local exclusive prefix
    lcur[t] = ex;
    if (t < NB) gdst[t] += goff[(size_t)t * NPART + p] - ex;
    __syncthreads();

    int lo = p * chunk, hi = min(E, lo + chunk), cnt = hi - lo;
    for (int i = lo + t; i < hi; i += 256) {
        int d = dst[i];
        int b = d >> BSHIFT;
        int slot = atomicAdd(&lcur[b], 1);
        stage[slot] = (unsigned int)src[i] | ((unsigned int)(d & (BNODES - 1)) << 17);
        sdest[slot] = gdst[b] + slot;
    }
    __syncthreads();
    for (int i = t; i < cnt; i += 256)       // consecutive i -> consecutive dest
        bbuf[sdest[i]] = stage[i];
}

// ===== L4: bsort (196 blocks) PARALLEL gemm1-with-LDS (391 blocks) =========
// 512 threads/block, 64 KB LDS union. bsort has <1 block/CU so the union
// costs it nothing; gemm1 gets its proven LDS-staged MFMA form back and
// fills the remaining CUs while bsort's latency-bound blocks run.
__global__ __launch_bounds__(512) void k_bsort_gemm1(const int* __restrict__ btot,
                                                     unsigned int* __restrict__ bbuf,
                                                     int* __restrict__ degi,
                                                     int* __restrict__ beg,
                                                     float* __restrict__ dinv,
                                                     int n, int NB,
                                                     const float* __restrict__ x,
                                                     const short* __restrict__ W1s,
                                                     short* __restrict__ hb) {
    __shared__ __align__(16) char smem[65536];
    int blk = blockIdx.x, t = threadIdx.x;

    if (blk < NB) {
        // -------- bsort path: per-bucket counting sort (512 threads) -------
        unsigned int* stage = (unsigned int*)smem;          // 36864 B
        int* hist  = (int*)(smem + 36864);                  //  2048 B
        int* cur   = (int*)(smem + 38912);                  //  2048 B
        int* lbase = (int*)(smem + 40960);                  //  1024 B
        int* wsum  = (int*)(smem + 41984);                  //    16 B
        int b = blk;

        // 512-thread-safe scan of btot (work on t<256, barriers outside)
        if (t < 256) {
            int v = (t < NB) ? btot[t] : 0;
            int incl = v;
            int lane = t & 63, w = t >> 6;
            #pragma unroll
            for (int off = 1; off < 64; off <<= 1) {
                int u = __shfl_up(incl, off, 64);
                if (lane >= off) incl += u;
            }
            if (lane == 63) wsum[w] = incl;
            lbase[t] = v;   // stash v
        }
        __syncthreads();
        if (t < 256) {
            int v = lbase[t];
            int incl = v;
            int lane = t & 63, w = t >> 6;
            #pragma unroll
            for (int off = 1; off < 64; off <<= 1) {
                int u = __shfl_up(incl, off, 64);
                if (lane >= off) incl += u;
            }
            int wadd = 0;
            for (int i = 0; i < w; ++i) wadd += wsum[i];
            lbase[t] = wadd + incl - v;
        }
        hist[t] = 0;                 // 512 counters, 512 threads
        __syncthreads();

        int cnt = min(btot[b], BCAPS);
        int gbase = lbase[b];
        int node0 = b << BSHIFT;

        for (int i = t; i < cnt; i += 512) {
            unsigned int p = bbuf[gbase + i];
            stage[i] = p;
            atomicAdd(&hist[p >> 17], 1);
        }
        __syncthreads();

        // exclusive scan of 512 counters: thread t<256 owns pair (2t, 2t+1)
        int v0 = 0, v1 = 0, ex = 0;
        if (t < 256) {
            v0 = hist[2 * t]; v1 = hist[2 * t + 1];
            int s = v0 + v1;
            int incl = s;
            int lane = t & 63, w = t >> 6;
            #pragma unroll
            for (int off = 1; off < 64; off <<= 1) {
                int u = __shfl_up(incl, off, 64);
                if (lane >= off) incl += u;
            }
            if (lane == 63) wsum[w] = incl;
            ex = incl - s;   // wave-local; add wadd after sync
        }
        __syncthreads();
        if (t < 256) {
            int w = t >> 6;
            int wadd = 0;
            for (int i = 0; i < w; ++i) wadd += wsum[i];
            ex += wadd;
            cur[2 * t] = ex;
            cur[2 * t + 1] = ex + v0;
            int nodeA = node0 + 2 * t, nodeB = node0 + 2 * t + 1;
            if (nodeA < n) {
                degi[nodeA] = v0;
                beg[nodeA]  = gbase + ex;
                dinv[nodeA] = rsqrtf((float)(v0 + 1));
            }
            if (nodeB < n) {
                degi[nodeB] = v1;
                beg[nodeB]  = gbase + ex + v0;
                dinv[nodeB] = rsqrtf((float)(v1 + 1));
            }
        }
        __syncthreads();

        for (int i = t; i < cnt; i += 512) {
            unsigned int p = stage[i];
            int slot = atomicAdd(&cur[p >> 17], 1);
            bbuf[gbase + slot] = p & 0x1FFFFu;
        }
    } else {
        // -------- gemm1 path: hb = bf16(x @ W1), 256 rows/block ------------
        short* lw = (short*)smem;     // 64 KB: full swizzled W1
        {
            const uint4* g = (const uint4*)W1s;
            uint4* l = (uint4*)lw;
            for (int i = t; i < 4096; i += 512) l[i] = g[i];
        }
        __syncthreads();

        int bid = blk - NB;
        int wave = t >> 6, lane = t & 63;
        int quad = lane >> 4, lrow = lane & 15;
        long long rowbase = (long long)bid * 256 + wave * 32;

        f32x4 acc[2][8];
        #pragma unroll
        for (int rt = 0; rt < 2; ++rt)
            #pragma unroll
            for (int nt = 0; nt < 8; ++nt) acc[rt][nt] = (f32x4){0.f, 0.f, 0.f, 0.f};

        const short8* lf = (const short8*)lw;

        #pragma unroll
        for (int kt = 0; kt < 8; ++kt) {
            int k0 = kt * 32 + quad * 8;
            short8 a[2];
            #pragma unroll
            for (int rt = 0; rt < 2; ++rt) {
                long long row = rowbase + rt * 16 + lrow;
                float4 v0 = {0.f,0.f,0.f,0.f}, v1 = {0.f,0.f,0.f,0.f};
                if (row < n) {
                    const float* xp = x + row * DIN + k0;
                    v0 = *(const float4*)xp;
                    v1 = *(const float4*)(xp + 4);
                }
                short8 av;
                av[0] = f2bf(v0.x); av[1] = f2bf(v0.y); av[2] = f2bf(v0.z); av[3] = f2bf(v0.w);
                av[4] = f2bf(v1.x); av[5] = f2bf(v1.y); av[6] = f2bf(v1.z); av[7] = f2bf(v1.w);
                a[rt] = av;
            }
            #pragma unroll
            for (int nt = 0; nt < 8; ++nt) {
                short8 b = lf[(kt * 8 + nt) * 64 + lane];
                acc[0][nt] = __builtin_amdgcn_mfma_f32_16x16x32_bf16(a[0], b, acc[0][nt], 0, 0, 0);
                acc[1][nt] = __builtin_amdgcn_mfma_f32_16x16x32_bf16(a[1], b, acc[1][nt], 0, 0, 0);
            }
        }
        #pragma unroll
        for (int rt = 0; rt < 2; ++rt)
            #pragma unroll
            for (int nt = 0; nt < 8; ++nt)
                #pragma unroll
                for (int r = 0; r < 4; ++r) {
                    long long row = rowbase + rt * 16 + quad * 4 + r;
                    if (row < n) hb[row * DHID + nt * 16 + lrow] = f2bf(acc[rt][nt][r]);
                }
    }
}

// ===== L5: gather1 — proven round-1 interleave, per-edge dinv ==============
// wave = 1 node; 4 edge-groups x 16 dim-lanes; 4 uint4 gathers in flight.
__global__ __launch_bounds__(256) void k_gather1(const int* __restrict__ beg,
                          const int* __restrict__ degi,
                          const int* __restrict__ ssrc, const float* __restrict__ dinv,
                          const uint4* __restrict__ hb4, const float* __restrict__ b1,
                          uint4* __restrict__ h1u4, int n) {
    int node = blockIdx.x * 4 + (threadIdx.x >> 6);
    int t = threadIdx.x & 63;
    if (node >= n) return;
    int cnt = degi[node];
    int bg  = beg[node];
    int grp = t >> 4, sub = t & 15;           // 4 edge-groups x 16 dim-lanes

    float a[8] = {0.f,0.f,0.f,0.f,0.f,0.f,0.f,0.f};
    int k = 0;
    for (; k + 16 <= cnt; k += 16) {          // 16 edges: 4 x 1KB wave-loads
        int s[4];
        #pragma unroll
        for (int q = 0; q < 4; ++q) s[q] = ssrc[bg + k + grp * 4 + q];
        float dv[4]; uint4 v[4];
        #pragma unroll
        for (int q = 0; q < 4; ++q) { dv[q] = dinv[s[q]]; v[q] = hb4[(size_t)s[q] * 16 + sub]; }
        #pragma unroll
        for (int q = 0; q < 4; ++q) fma8(a, v[q], dv[q]);
    }
    for (; k < cnt; k += 4) {                 // predicated tail quad
        int idx = k + grp;
        if (idx < cnt) {
            int s = ssrc[bg + idx];
            fma8(a, hb4[(size_t)s * 16 + sub], dinv[s]);
        }
    }

    #pragma unroll
    for (int j = 0; j < 8; ++j) {             // combine the 4 edge-groups
        a[j] += __shfl_xor(a[j], 16);
        a[j] += __shfl_xor(a[j], 32);
    }

    if (grp == 0) {                           // 16 lanes write the 256B row
        uint4 sv = hb4[(size_t)node * 16 + sub];
        float di = dinv[node], dd = di * di;
        float4 bA = ((const float4*)b1)[sub * 2];
        float4 bB = ((const float4*)b1)[sub * 2 + 1];
        float v0 = fmaxf(di * a[0] + dd * bfu(sv.x) + bA.x, 0.f);
        float v1 = fmaxf(di * a[1] + dd * bfh(sv.x) + bA.y, 0.f);
        float v2 = fmaxf(di * a[2] + dd * bfu(sv.y) + bA.z, 0.f);
        float v3 = fmaxf(di * a[3] + dd * bfh(sv.y) + bA.w, 0.f);
        float v4 = fmaxf(di * a[4] + dd * bfu(sv.z) + bB.x, 0.f);
        float v5 = fmaxf(di * a[5] + dd * bfh(sv.z) + bB.y, 0.f);
        float v6 = fmaxf(di * a[6] + dd * bfu(sv.w) + bB.z, 0.f);
        float v7 = fmaxf(di * a[7] + dd * bfh(sv.w) + bB.w, 0.f);
        uint4 o;
        o.x = pack2(v0, v1);
        o.y = pack2(v2, v3);
        o.z = pack2(v4, v5);
        o.w = pack2(v6, v7);
        h1u4[(size_t)node * 16 + sub] = o;    // 4 consecutive rows/wave = 1KB
    }
}

// ==== L6: gemm2: h2b[n,48] = bf16( (h1b @ W2[:, :48]) * dinv[row] ) ========
// 48 cols cover NCLS=47 -> 96B rows, 25% less gather2 traffic.
__global__ __launch_bounds__(256) void k_gemm2_mfma(const short* __restrict__ h1b,
                                                    const short* __restrict__ W2s,
                                                    const float* __restrict__ dinv,
                                                    short* __restrict__ h2b, int n) {
    __shared__ short lw[8192];  // 16 KB: swizzled padded W2
    {
        const uint4* g = (const uint4*)W2s;
        uint4* l = (uint4*)lw;
        for (int i = threadIdx.x; i < 1024; i += 256) l[i] = g[i];
    }
    __syncthreads();

    int wave = threadIdx.x >> 6, lane = threadIdx.x & 63;
    int quad = lane >> 4, lrow = lane & 15;
    long long row0 = (long long)blockIdx.x * 64 + wave * 16;

    f32x4 acc[3];
    #pragma unroll
    for (int nt = 0; nt < 3; ++nt) acc[nt] = (f32x4){0.f, 0.f, 0.f, 0.f};

    const short8* lf = (const short8*)lw;

    #pragma unroll
    for (int kt = 0; kt < 4; ++kt) {
        long long row = row0 + lrow;
        short8 a = (short8){0,0,0,0,0,0,0,0};
        if (row < n) a = *(const short8*)(h1b + row * DHID + kt * 32 + quad * 8);
        #pragma unroll
        for (int nt = 0; nt < 3; ++nt)
            acc[nt] = __builtin_amdgcn_mfma_f32_16x16x32_bf16(a, lf[(kt * 4 + nt) * 64 + lane], acc[nt], 0, 0, 0);
    }
    float dvv[4];
    #pragma unroll
    for (int r = 0; r < 4; ++r) {
        long long row = row0 + quad * 4 + r;
        dvv[r] = (row < n) ? dinv[row] : 0.f;
    }
    #pragma unroll
    for (int nt = 0; nt < 3; ++nt)
        #pragma unroll
        for (int r = 0; r < 4; ++r) {
            long long row = row0 + quad * 4 + r;
            if (row < n) h2b[row * 48 + nt * 16 + lrow] = f2bf(acc[nt][r] * dvv[r]);
        }
}

// ===== L7: gather2 (96B prescaled rows => pure load/add inner loop) ========
__global__ __launch_bounds__(256) void k_gather2(const int* __restrict__ beg,
                          const int* __restrict__ degi,
                          const int* __restrict__ ssrc, const float* __restrict__ dinv,
                          const uint4* __restrict__ h2b6, const float* __restrict__ b2,
                          float* __restrict__ out, int n) {
    int node = blockIdx.x * 4 + (threadIdx.x >> 6);
    int t = threadIdx.x & 63;
    if (node >= n) return;
    int cnt = degi[node];
    int bg  = beg[node];
    int grp = t >> 3, sub = t & 7;            // 8 edge-groups x 8 dim-lanes (sub<6 live)

    float a[8] = {0.f,0.f,0.f,0.f,0.f,0.f,0.f,0.f};
    int k = 0;
    for (; k + 16 <= cnt; k += 16) {          // 16 edges: 2 x 768B wave-loads
        int s0 = ssrc[bg + k + grp], s1 = ssrc[bg + k + 8 + grp];
        if (sub < 6) {
            uint4 v0 = h2b6[(size_t)s0 * 6 + sub];
            uint4 v1 = h2b6[(size_t)s1 * 6 + sub];
            add8(a, v0); add8(a, v1);
        }
    }
    for (; k < cnt; k += 8) {                 // predicated tail octet
        int idx = k + grp;
        if (idx < cnt) {
            int s = ssrc[bg + idx];
            if (sub < 6) add8(a, h2b6[(size_t)s * 6 + sub]);
        }
    }
    if (grp == 0 && sub < 6) add8(a, h2b6[(size_t)node * 6 + sub]);   // self

    #pragma unroll
    for (int j = 0; j < 8; ++j) {             // combine the 8 edge-groups
        a[j] += __shfl_xor(a[j], 8);
        a[j] += __shfl_xor(a[j], 16);
        a[j] += __shfl_xor(a[j], 32);
    }

    if (grp == 0) {
        float di = dinv[node];
        #pragma unroll
        for (int j = 0; j < 8; ++j) {
            int c = sub * 8 + j;
            if (c < NCLS) out[(size_t)node * NCLS + c] = di * a[j] + b2[c];
        }
    }
}

// ===========================================================================
extern "C" void kernel_launch(void* const* d_in, const int* in_sizes, int n_in,
                              void* d_out, int out_size, void* d_ws, size_t ws_size,
                              hipStream_t stream) {
    const float* x  = (const float*)d_in[0];
    const int*   ei = (const int*)d_in[1];
    const float* W1 = (const float*)d_in[2];
    const float* b1 = (const float*)d_in[3];
    const float* W2 = (const float*)d_in[4];
    const float* b2 = (const float*)d_in[5];

    const int n = in_sizes[0] / DIN;   // 100000
    const int E = in_sizes[1] / 2;     // 1600000
    const int* src = ei;
    const int* dst = ei + E;
    float* out = (float*)d_out;

    const int NB = (n + BNODES - 1) >> BSHIFT;   // 196 buckets
    const int chunk = (E + NPART - 1) / NPART;   // 1563

    // workspace layout (~49 MB)
    char* w = (char*)d_ws;
    int*   ghist = (int*)w;                    w += (size_t)NB * NPART * 4;   // 800 KB (transposed)
    int*   goff  = (int*)w;                    w += (size_t)NB * NPART * 4;   // 800 KB
    int*   btot  = (int*)w;                    w += ((size_t)256 * 4);
    int*   degi  = (int*)w;                    w += (size_t)n * 4;
    int*   beg   = (int*)w;                    w += (size_t)n * 4;
    float* dinv  = (float*)w;                  w += (size_t)n * 4;
    short* W1s   = (short*)w;                  w += (size_t)32768 * 2;        // 64 KB
    short* W2s   = (short*)w;                  w += (size_t)8192 * 2;         // 16 KB
    unsigned int* bbuf = (unsigned int*)w;     w += (size_t)E * 4;            // CSR src
    short* hb    = (short*)w;                  w += (size_t)n * DHID * 2;     // bf16 x@W1
    short* h1b   = (short*)w;                  w += (size_t)n * DHID * 2;     // bf16 relu layer1
    short* h2b   = (short*)w;                  w += (size_t)n * 48 * 2;       // bf16 (h1@W2)*dinv, 48 cols

    // L1: weight swizzles + per-partition histogram (1044 blocks)
    k_prep_hist<<<20 + NPART, 256, 0, stream>>>(W1, W2, W1s, W2s, dst, ghist, E, NB, chunk);
    // L2: column scan -> goff, btot (196 blocks, int4)
    k_colscan<<<NB, 256, 0, stream>>>(ghist, goff, btot);
    // L3: scatter (standalone, light LDS, high occupancy)
    k_scatter<<<NPART, 256, 0, stream>>>(src, dst, ghist, goff, btot, bbuf, E, NB, chunk);
    // L4: bsort (196 blocks) || gemm1-with-LDS (391 blocks, 256 rows each)
    k_bsort_gemm1<<<NB + (n + 255) / 256, 512, 0, stream>>>(btot, bbuf, degi, beg, dinv,
                                                            n, NB, x, W1s, hb);
    // L5: gather1 (fused bias+self+relu, bf16 out)
    k_gather1<<<(n + 3) / 4, 256, 0, stream>>>(beg, degi, (const int*)bbuf, dinv,
                                               (const uint4*)hb, b1,
                                               (uint4*)h1b, n);
    // L6: gemm2 (prescales 48-col h2b by dinv[row])
    k_gemm2_mfma<<<(n + 63) / 64, 256, 0, stream>>>(h1b, W2s, dinv, h2b, n);
    // L7: gather2 (fused bias+self)
    k_gather2<<<(n + 3) / 4, 256, 0, stream>>>(beg, degi, (const int*)bbuf, dinv,
                                               (const uint4*)h2b, b2, out, n);
}